// Round 9
// baseline (443.861 us; speedup 1.0000x reference)
//
#include <hip/hip_runtime.h>
#include <cmath>

constexpr int BB = 4, CC = 64, HH = 256, WW = 256;
constexpr int WP = 258;   // padded width: cols -1..256 stored at col+1
constexpr int C2R = 257;  // c2 rows -1..255 stored at r+1
constexpr unsigned NB = 1024;  // grid size; 4 blocks/CU on 256 CUs

typedef short short8 __attribute__((ext_vector_type(8)));
typedef float f32x4 __attribute__((ext_vector_type(4)));
#define MFMA_BF16 __builtin_amdgcn_mfma_f32_16x16x32_bf16

union U16x8 { uint4 v; unsigned short h[8]; };
union U16x4 { uint2 v; unsigned short h[4]; };

__device__ inline unsigned short f2bf(float f) {
  unsigned u = __builtin_bit_cast(unsigned, f);
  u += 0x7fffu + ((u >> 16) & 1u);
  return (unsigned short)(u >> 16);
}
__device__ inline unsigned short f2bf_trunc(float f) {
  return (unsigned short)(__builtin_bit_cast(unsigned, f) >> 16);
}
__device__ inline float bf2f(unsigned short h) {
  unsigned u = ((unsigned)h) << 16;
  return __builtin_bit_cast(float, u);
}

// ---------------------------------------------------------------------------
// Device-scope grid barrier. All NB blocks are co-resident (guaranteed by
// LDS 34 KB/block + launch_bounds(256,4) -> exactly 4 blocks/CU x 256 CUs).
// Release: __threadfence (agent-scope wb) before arrive; acquire: agent-scope
// flag load + __threadfence (inv) after. Bounded spin (~1s) so a residency
// failure shows as wrong output, not a hang.
// ---------------------------------------------------------------------------
__device__ inline void gridBarrier(unsigned* cnt, unsigned* flag) {
  __syncthreads();
  if (threadIdx.x == 0) {
    __threadfence();
    unsigned prev = atomicAdd(cnt, 1u);
    if (prev == NB - 1u) {
      __hip_atomic_store(flag, 1u, __ATOMIC_RELEASE, __HIP_MEMORY_SCOPE_AGENT);
    } else {
      for (int i = 0; i < (1 << 22); ++i) {
        if (__hip_atomic_load(flag, __ATOMIC_RELAXED,
                              __HIP_MEMORY_SCOPE_AGENT) != 0u)
          break;
        __builtin_amdgcn_s_sleep(8);
      }
    }
    __threadfence();
  }
  __syncthreads();
}

// ---------------------------------------------------------------------------
// Fused persistent kernel: phase1 pack(+wpack) | barrier | phase2 lower conv
// | barrier | phase3 final conv. Phase bodies are the round-8 kernels.
// ---------------------------------------------------------------------------
__global__ __launch_bounds__(256, 4) void k_fused(
    const float* __restrict__ x, const float* __restrict__ Wt,
    float* __restrict__ s, unsigned short* __restrict__ Wp,
    unsigned short* __restrict__ xn, unsigned short* __restrict__ c2,
    float* __restrict__ out, unsigned* __restrict__ bar) {
  __shared__ __align__(16) float smem[8512];  // max(pack 34048 B, conv 33792 B)
  const int t = threadIdx.x;
  const int bid = blockIdx.x;

  // ===== phase 1: wpack (blocks 0..17) + pack (1 row per block, 2 halves) ===
  if (bid < 18) {
    int gid = bid * 256 + t;  // 4608 total
    int lane = gid & 63, kc = (gid >> 6) & 1, mt = (gid >> 7) & 3, tap = gid >> 9;
    int o = mt * 16 + (lane & 15);
    int kb = kc * 32 + (lane >> 4) * 8;
    int ky = tap / 3, kx = tap % 3;
    U16x8 r;
#pragma unroll
    for (int j = 0; j < 8; ++j)
      r.h[j] = f2bf(Wt[o * 576 + (kb + j) * 9 + ky * 3 + kx]);
    ((uint4*)Wp)[gid] = r.v;
  }
  {
    float* tile = smem;          // CC*129 floats
    float* pmax = smem + 8256;   // 2*128 floats
    const int b = bid >> 8, y = bid & 255;
    uint4* xn4 = (uint4*)xn;
#pragma unroll 1
    for (int half = 0; half < 2; ++half) {
      __syncthreads();
      const int px0 = half * 128;
      const int pxl = t & 127, chb = (t >> 7) * 32;
      const float* base =
          x + (size_t)b * CC * HH * WW + (size_t)y * WW + px0 + pxl;
      float m = -1e30f;
#pragma unroll 8
      for (int i = 0; i < 32; ++i) {
        float v = base[(size_t)(chb + i) * HH * WW];
        tile[(chb + i) * 129 + pxl] = v;
        m = fmaxf(m, v);
      }
      pmax[(t >> 7) * 128 + pxl] = m;
      if (t < 8) {
        int col = half ? (WP - 1) : 0;
        xn4[(((size_t)(b * HH + y) * WP + col) * CC + t * 8) >> 3] =
            make_uint4(0, 0, 0, 0);
      }
      __syncthreads();
      if (t < 128) {
        float mm = fmaxf(pmax[t], pmax[128 + t]);
        s[(b * HH + y) * WW + px0 + t] = 25.0f / fminf(fmaxf(mm, 1.0f), 50.0f);
      }
#pragma unroll
      for (int g = 0; g < 4; ++g) {
        int px = g * 32 + (t >> 3), c8 = t & 7;
        U16x8 r;
#pragma unroll
        for (int j = 0; j < 8; ++j) r.h[j] = f2bf(tile[(c8 * 8 + j) * 129 + px]);
        xn4[(((size_t)(b * HH + y) * WP + px0 + px + 1) * CC + c8 * 8) >> 3] = r.v;
      }
    }
  }
  gridBarrier(bar + 0, bar + 1);

  // ===== phase 2: lower conv (warp-on-the-fly), tasks 2064 =====
  {
    uint4* lds = (uint4*)smem;
    const uint4* xn4 = (const uint4*)xn;
    const uint4* wp4 = (const uint4*)Wp;
    const int lane = t & 63, w = t >> 6;
    const int ow = w & 1, ch2 = w >> 1;
    const int quad = lane >> 4, l15 = lane & 15;
#pragma unroll 1
    for (int task = bid; task < 2064; task += NB) {
      const int b = task / 516;
      const int rem = task % 516;
      const int ctile = rem & 3, tr = rem >> 2;
      const int r0 = tr * 2 - 1;
      const int colBase = ctile * 64;
      __syncthreads();  // previous iteration's LDS reads done
#pragma unroll 1
      for (int g = 0; g < 3; ++g) {
        float w0a[3], w1a[3];
        int o0a[3], o1a[3], la[3];
        bool act[3], va[3];
#pragma unroll
        for (int j = 0; j < 3; ++j) {
          int idx = (g * 3 + j) * 256 + t;
          act[j] = idx < 2112;
          int rr_ = idx / 528, rm = idx % 528;
          int col_ = rm >> 3, ch_ = rm & 7;
          int xrow = r0 - 1 + rr_;
          va[j] = act[j] && (xrow >= 0) && (xrow < HH);
          la[j] = (rr_ * 66 + col_) * 8 + (ch_ ^ (col_ & 7));
          float sv = 0.0f;
          int pxc = min(max(colBase + col_ - 1, 0), WW - 1);
          if (va[j]) sv = s[(b * HH + min(max(xrow, 0), HH - 1)) * WW + pxc];
          float ys = (float)xrow - sv;
          float fy = floorf(ys);
          float wfr = ys - fy;
          int i0 = (int)fy;
          w0a[j] = (i0 >= 0) ? 1.0f - wfr : 0.0f;
          w1a[j] = (i0 + 1 >= 0) ? wfr : 0.0f;
          int a0 = min(max(i0, 0), HH - 1), a1 = min(max(i0 + 1, 0), HH - 1);
          o0a[j] = ((b * HH + a0) * WP + colBase + col_) * 8 + ch_;
          o1a[j] = ((b * HH + a1) * WP + colBase + col_) * 8 + ch_;
        }
#pragma unroll
        for (int j = 0; j < 3; ++j) {
          if (act[j]) {
            uint4 v = make_uint4(0, 0, 0, 0);
            if (va[j]) {
              U16x8 u0, u1, rr;
              u0.v = xn4[o0a[j]];
              u1.v = xn4[o1a[j]];
#pragma unroll
              for (int k = 0; k < 8; ++k)
                rr.h[k] =
                    f2bf_trunc(w0a[j] * bf2f(u0.h[k]) + w1a[j] * bf2f(u1.h[k]));
              v = rr.v;
            }
            lds[la[j]] = v;
          }
        }
      }

      f32x4 acc[2][2][2];
#pragma unroll
      for (int pt = 0; pt < 2; ++pt)
#pragma unroll
        for (int rr = 0; rr < 2; ++rr)
#pragma unroll
          for (int ct = 0; ct < 2; ++ct) acc[pt][rr][ct] = {0.f, 0.f, 0.f, 0.f};
      __syncthreads();

#pragma unroll 1
      for (int kc = 0; kc < 2; ++kc) {
        short8 wf[9][2];
#pragma unroll
        for (int tap = 0; tap < 9; ++tap)
#pragma unroll
          for (int ct = 0; ct < 2; ++ct)
            wf[tap][ct] = __builtin_bit_cast(
                short8, wp4[((tap * 4 + (ow * 2 + ct)) * 2 + kc) * 64 + lane]);
#pragma unroll
        for (int pt = 0; pt < 2; ++pt) {
#pragma unroll
          for (int ir = 0; ir < 4; ++ir) {
#pragma unroll
            for (int kx = 0; kx < 3; ++kx) {
              int col = ch2 * 32 + pt * 16 + l15 + kx;
              short8 xf = __builtin_bit_cast(
                  short8, lds[(ir * 66 + col) * 8 + ((kc * 4 + quad) ^ (col & 7))]);
              if (ir <= 2) {
#pragma unroll
                for (int ct = 0; ct < 2; ++ct)
                  acc[pt][0][ct] =
                      MFMA_BF16(wf[ir * 3 + kx][ct], xf, acc[pt][0][ct], 0, 0, 0);
              }
              if (ir >= 1) {
#pragma unroll
                for (int ct = 0; ct < 2; ++ct)
                  acc[pt][1][ct] = MFMA_BF16(wf[(ir - 1) * 3 + kx][ct], xf,
                                             acc[pt][1][ct], 0, 0, 0);
              }
            }
          }
        }
      }

      uint2* c2u = (uint2*)c2;
#pragma unroll
      for (int pt = 0; pt < 2; ++pt) {
        int px = colBase + ch2 * 32 + pt * 16 + l15;
#pragma unroll
        for (int rr = 0; rr < 2; ++rr) {
          int r = r0 + rr;
          if (r > 255) continue;
#pragma unroll
          for (int ct = 0; ct < 2; ++ct) {
            f32x4 A = acc[pt][rr][ct];
            int og = (ow * 2 + ct) * 4 + quad;
            unsigned short h0 = f2bf(A[0]), h1 = f2bf(A[1]), h2 = f2bf(A[2]),
                           h3 = f2bf(A[3]);
            uint2 val = make_uint2((unsigned)h0 | ((unsigned)h1 << 16),
                                   (unsigned)h2 | ((unsigned)h3 << 16));
            c2u[(size_t)((b * 16 + og) * C2R + (r + 1)) * WW + px] = val;
          }
        }
      }
    }
  }
  gridBarrier(bar + 2, bar + 3);

  // ===== phase 3: final conv + c2 resample + min, tasks 2048 =====
  {
    uint4* lds = (uint4*)smem;
    const uint4* src4 = (const uint4*)xn;
    const uint4* wp4 = (const uint4*)Wp;
    const uint2* c2u = (const uint2*)c2;
    const int lane = t & 63, w = t >> 6;
    const int ow = w & 1, ch2 = w >> 1;
    const int quad = lane >> 4, l15 = lane & 15;
#pragma unroll 1
    for (int task = bid; task < 2048; task += NB) {
      const int b = task >> 9;
      const int rem = task & 511;
      const int ctile = rem & 3, tr = rem >> 2;
      const int y0 = tr * 2;
      const int colBase = ctile * 64;
      __syncthreads();
#pragma unroll 1
      for (int i = 0; i < 9; ++i) {
        int idx = i * 256 + t;
        if (idx < 2112) {
          int rr_ = idx / 528, rm = idx % 528;
          int col_ = rm >> 3, ch_ = rm & 7;
          int xrow = y0 - 1 + rr_;
          uint4 v = make_uint4(0, 0, 0, 0);
          if (xrow >= 0 && xrow < HH)
            v = src4[((size_t)(b * HH + xrow) * WP + colBase + col_) * 8 + ch_];
          lds[(rr_ * 66 + col_) * 8 + (ch_ ^ (col_ & 7))] = v;
        }
      }

      f32x4 acc[2][2][2];
#pragma unroll
      for (int pt = 0; pt < 2; ++pt)
#pragma unroll
        for (int rr = 0; rr < 2; ++rr)
#pragma unroll
          for (int ct = 0; ct < 2; ++ct) acc[pt][rr][ct] = {0.f, 0.f, 0.f, 0.f};
      __syncthreads();

#pragma unroll 1
      for (int kc = 0; kc < 2; ++kc) {
        short8 wf[9][2];
#pragma unroll
        for (int tap = 0; tap < 9; ++tap)
#pragma unroll
          for (int ct = 0; ct < 2; ++ct)
            wf[tap][ct] = __builtin_bit_cast(
                short8, wp4[((tap * 4 + (ow * 2 + ct)) * 2 + kc) * 64 + lane]);
#pragma unroll
        for (int pt = 0; pt < 2; ++pt) {
#pragma unroll
          for (int ir = 0; ir < 4; ++ir) {
#pragma unroll
            for (int kx = 0; kx < 3; ++kx) {
              int col = ch2 * 32 + pt * 16 + l15 + kx;
              short8 xf = __builtin_bit_cast(
                  short8, lds[(ir * 66 + col) * 8 + ((kc * 4 + quad) ^ (col & 7))]);
              if (ir <= 2) {
#pragma unroll
                for (int ct = 0; ct < 2; ++ct)
                  acc[pt][0][ct] =
                      MFMA_BF16(wf[ir * 3 + kx][ct], xf, acc[pt][0][ct], 0, 0, 0);
              }
              if (ir >= 1) {
#pragma unroll
                for (int ct = 0; ct < 2; ++ct)
                  acc[pt][1][ct] = MFMA_BF16(wf[(ir - 1) * 3 + kx][ct], xf,
                                             acc[pt][1][ct], 0, 0, 0);
              }
            }
          }
        }
      }

#pragma unroll
      for (int pt = 0; pt < 2; ++pt) {
        int px = colBase + ch2 * 32 + pt * 16 + l15;
#pragma unroll
        for (int rr = 0; rr < 2; ++rr) {
          int y = y0 + rr;
          float sv = s[(b * HH + y) * WW + px];
          float ys = (float)y - sv;
          float fy = floorf(ys);
          float wfr = ys - fy;
          int i0 = (int)fy;
          float lw0 = (i0 + 1 >= 0 && i0 + 1 <= HH) ? 1.0f - wfr : 0.0f;
          float lw1 = (i0 + 2 >= 0 && i0 + 2 <= HH) ? wfr : 0.0f;
          int a0 = min(max(i0 + 1, 0), HH);
          int a1 = min(max(i0 + 2, 0), HH);
#pragma unroll
          for (int ct = 0; ct < 2; ++ct) {
            f32x4 A = acc[pt][rr][ct];
            int og = (ow * 2 + ct) * 4 + quad;
            U16x4 v0, v1;
            v0.v = c2u[(size_t)((b * 16 + og) * C2R + a0) * WW + px];
            v1.v = c2u[(size_t)((b * 16 + og) * C2R + a1) * WW + px];
#pragma unroll
            for (int reg = 0; reg < 4; ++reg) {
              float lower = lw0 * bf2f(v0.h[reg]) + lw1 * bf2f(v1.h[reg]);
              out[((size_t)(b * CC + og * 4 + reg) * HH + y) * WW + px] =
                  fminf(A[reg], lower);
            }
          }
        }
      }
    }
  }
}

// ---------------------------------------------------------------------------
extern "C" void kernel_launch(void* const* d_in, const int* in_sizes, int n_in,
                              void* d_out, int out_size, void* d_ws, size_t ws_size,
                              hipStream_t stream) {
  const float* x = (const float*)d_in[0];
  const float* Wt = (const float*)d_in[1];
  float* out = (float*)d_out;

  char* ws = (char*)d_ws;
  unsigned* bar = (unsigned*)ws;                            //        64 B used
  float* s = (float*)(ws + 1024);                           // 1,048,576 B
  unsigned short* Wp = (unsigned short*)(ws + 1049600);     //    73,728 B
  unsigned short* xn = (unsigned short*)(ws + 1123328);     // 33,816,576 B
  unsigned short* c2 = (unsigned short*)(ws + 34939904);    // 33,685,504 B
                                                            // total 68.6 MB
  hipMemsetAsync(bar, 0, 64, stream);  // zero barrier counters/flags
  k_fused<<<dim3(NB), 256, 0, stream>>>(x, Wt, s, Wp, xn, c2, out, bar);
}

// Round 10
// 190.653 us; speedup vs baseline: 2.3281x; 2.3281x over previous
//
#include <hip/hip_runtime.h>
#include <cmath>

constexpr int BB = 4, CC = 64, HH = 256, WW = 256;
constexpr int WP = 258;   // padded width: cols -1..256 stored at col+1
constexpr int C2R = 257;  // c2 rows -1..255 stored at r+1

typedef short short8 __attribute__((ext_vector_type(8)));
typedef float f32x4 __attribute__((ext_vector_type(4)));
#define MFMA_BF16 __builtin_amdgcn_mfma_f32_16x16x32_bf16

union U16x8 { uint4 v; unsigned short h[8]; };
union U16x4 { uint2 v; unsigned short h[4]; };

__device__ inline unsigned short f2bf(float f) {
  unsigned u = __builtin_bit_cast(unsigned, f);
  u += 0x7fffu + ((u >> 16) & 1u);
  return (unsigned short)(u >> 16);
}
__device__ inline unsigned short f2bf_trunc(float f) {
  return (unsigned short)(__builtin_bit_cast(unsigned, f) >> 16);
}
__device__ inline float bf2f(unsigned short h) {
  unsigned u = ((unsigned)h) << 16;
  return __builtin_bit_cast(float, u);
}

// ---------------------------------------------------------------------------
// k_pack: blocks x<512: half-row (128 px) NCHW fp32 -> col-padded NHWC bf16 +
// fused channel-max -> s (x loads non-temporal: read-once, keep L2 for xn/c2).
// Blocks x in [512,530), y==0: weight repack (former k_wpack).
// ---------------------------------------------------------------------------
__global__ __launch_bounds__(256, 4) void k_pack(const float* __restrict__ x,
                                                 const float* __restrict__ Wt,
                                                 float* __restrict__ s,
                                                 unsigned short* __restrict__ Wp,
                                                 unsigned short* __restrict__ xn) {
  __shared__ float tile[CC * 129];
  __shared__ float pmax[2][128];
  const int t = threadIdx.x;

  if (blockIdx.x >= 512) {  // weight repack, 18 blocks on y==0
    if (blockIdx.y == 0) {
      int gid = (blockIdx.x - 512) * 256 + t;  // 4608 total
      int lane = gid & 63, kc = (gid >> 6) & 1, mt = (gid >> 7) & 3, tap = gid >> 9;
      int o = mt * 16 + (lane & 15);
      int kb = kc * 32 + (lane >> 4) * 8;
      int ky = tap / 3, kx = tap % 3;
      U16x8 r;
#pragma unroll
      for (int j = 0; j < 8; ++j)
        r.h[j] = f2bf(Wt[o * 576 + (kb + j) * 9 + ky * 3 + kx]);
      ((uint4*)Wp)[gid] = r.v;
    }
    return;
  }

  const int half = blockIdx.x & 1, y = blockIdx.x >> 1, b = blockIdx.y;
  const int px0 = half * 128;
  const int pxl = t & 127, chb = (t >> 7) * 32;

  const float* base = x + (size_t)b * CC * HH * WW + (size_t)y * WW + px0 + pxl;
  float m = -1e30f;
#pragma unroll 8
  for (int i = 0; i < 32; ++i) {
    float v = __builtin_nontemporal_load(base + (size_t)(chb + i) * HH * WW);
    tile[(chb + i) * 129 + pxl] = v;
    m = fmaxf(m, v);
  }
  pmax[t >> 7][pxl] = m;

  uint4* xn4 = (uint4*)xn;
  if (t < 8) {
    int col = half ? (WP - 1) : 0;
    xn4[(((size_t)(b * HH + y) * WP + col) * CC + t * 8) >> 3] =
        make_uint4(0, 0, 0, 0);
  }
  __syncthreads();

  if (t < 128) {
    float mm = fmaxf(pmax[0][t], pmax[1][t]);
    s[(b * HH + y) * WW + px0 + t] = 25.0f / fminf(fmaxf(mm, 1.0f), 50.0f);
  }
#pragma unroll
  for (int g = 0; g < 4; ++g) {
    int px = g * 32 + (t >> 3), c8 = t & 7;
    U16x8 r;
#pragma unroll
    for (int j = 0; j < 8; ++j) r.h[j] = f2bf(tile[(c8 * 8 + j) * 129 + px]);
    xn4[(((size_t)(b * HH + y) * WP + px0 + px + 1) * CC + c8 * 8) >> 3] = r.v;
  }
}

// ---------------------------------------------------------------------------
// Conv tile: block = 2 out rows x 64 cols x 64 och.
// LDS: 4 input rows x 66 padded cols x 8 chunks(8ch) uint4 = 33.8 KB
// -> 4 blocks/CU. Waves: ow = w&1 (32-och half), ch2 = w>>1 (32-col half).
// c2 layout: [b][og=och/4][row+1][px][4och] bf16 -> uint2 per (og,row,px).
// ---------------------------------------------------------------------------
__global__ __launch_bounds__(256, 4) void k_lower(const unsigned short* __restrict__ xn,
                                                  const unsigned short* __restrict__ Wp,
                                                  const float* __restrict__ s,
                                                  unsigned short* __restrict__ c2) {
  __shared__ uint4 lds[2112];
  const int t = threadIdx.x;
  const int ctile = blockIdx.x & 3, tr = blockIdx.x >> 2;
  const int b = blockIdx.y;
  const int r0 = tr * 2 - 1;          // out rows r0, r0+1 in [-1, 256]
  const int colBase = ctile * 64;

  const uint4* xn4 = (const uint4*)xn;
  // staging: 4 x2 rows (r0-1 .. r0+2) blended on the fly, groups of 3 iters
#pragma unroll 1
  for (int g = 0; g < 3; ++g) {
    float w0a[3], w1a[3];
    int o0a[3], o1a[3], la[3];
    bool act[3], va[3];
#pragma unroll
    for (int j = 0; j < 3; ++j) {
      int idx = (g * 3 + j) * 256 + t;
      act[j] = idx < 2112;
      int rr_ = idx / 528, rm = idx % 528;  // 528 = 66 cols * 8 chunks
      int col_ = rm >> 3, ch_ = rm & 7;
      int xrow = r0 - 1 + rr_;  // x2 row, [-2..258]
      va[j] = act[j] && (xrow >= 0) && (xrow < HH);
      la[j] = (rr_ * 66 + col_) * 8 + (ch_ ^ (col_ & 7));
      float sv = 0.0f;
      int pxc = min(max(colBase + col_ - 1, 0), WW - 1);
      if (va[j]) sv = s[(b * HH + min(max(xrow, 0), HH - 1)) * WW + pxc];
      float ys = (float)xrow - sv;
      float fy = floorf(ys);
      float wfr = ys - fy;
      int i0 = (int)fy;
      w0a[j] = (i0 >= 0) ? 1.0f - wfr : 0.0f;
      w1a[j] = (i0 + 1 >= 0) ? wfr : 0.0f;
      int a0 = min(max(i0, 0), HH - 1), a1 = min(max(i0 + 1, 0), HH - 1);
      o0a[j] = ((b * HH + a0) * WP + colBase + col_) * 8 + ch_;
      o1a[j] = ((b * HH + a1) * WP + colBase + col_) * 8 + ch_;
    }
#pragma unroll
    for (int j = 0; j < 3; ++j) {
      if (act[j]) {
        uint4 v = make_uint4(0, 0, 0, 0);
        if (va[j]) {
          U16x8 u0, u1, rr;
          u0.v = xn4[o0a[j]];
          u1.v = xn4[o1a[j]];
#pragma unroll
          for (int k = 0; k < 8; ++k)
            rr.h[k] = f2bf_trunc(w0a[j] * bf2f(u0.h[k]) + w1a[j] * bf2f(u1.h[k]));
          v = rr.v;
        }
        lds[la[j]] = v;
      }
    }
  }

  const int lane = t & 63, w = t >> 6;
  const int ow = w & 1, ch2 = w >> 1;
  const int quad = lane >> 4, l15 = lane & 15;
  const uint4* wp4 = (const uint4*)Wp;
  __syncthreads();

  f32x4 acc[2][2][2];  // [pt][rr][ct]
#pragma unroll
  for (int pt = 0; pt < 2; ++pt)
#pragma unroll
    for (int rr = 0; rr < 2; ++rr)
#pragma unroll
      for (int ct = 0; ct < 2; ++ct) acc[pt][rr][ct] = {0.f, 0.f, 0.f, 0.f};

#pragma unroll 1
  for (int kc = 0; kc < 2; ++kc) {
    short8 wf[9][2];
#pragma unroll
    for (int tap = 0; tap < 9; ++tap)
#pragma unroll
      for (int ct = 0; ct < 2; ++ct)
        wf[tap][ct] = __builtin_bit_cast(
            short8, wp4[((tap * 4 + (ow * 2 + ct)) * 2 + kc) * 64 + lane]);
#pragma unroll
    for (int pt = 0; pt < 2; ++pt) {
#pragma unroll
      for (int ir = 0; ir < 4; ++ir) {
#pragma unroll
        for (int kx = 0; kx < 3; ++kx) {
          int col = ch2 * 32 + pt * 16 + l15 + kx;
          short8 xf = __builtin_bit_cast(
              short8, lds[(ir * 66 + col) * 8 + ((kc * 4 + quad) ^ (col & 7))]);
          if (ir <= 2) {
#pragma unroll
            for (int ct = 0; ct < 2; ++ct)
              acc[pt][0][ct] = MFMA_BF16(wf[ir * 3 + kx][ct], xf, acc[pt][0][ct], 0, 0, 0);
          }
          if (ir >= 1) {
#pragma unroll
            for (int ct = 0; ct < 2; ++ct)
              acc[pt][1][ct] = MFMA_BF16(wf[(ir - 1) * 3 + kx][ct], xf, acc[pt][1][ct], 0, 0, 0);
          }
        }
      }
    }
  }

  uint2* c2u = (uint2*)c2;
#pragma unroll
  for (int pt = 0; pt < 2; ++pt) {
    int px = colBase + ch2 * 32 + pt * 16 + l15;
#pragma unroll
    for (int rr = 0; rr < 2; ++rr) {
      int r = r0 + rr;
      if (r > 255) continue;
#pragma unroll
      for (int ct = 0; ct < 2; ++ct) {
        f32x4 A = acc[pt][rr][ct];
        int og = (ow * 2 + ct) * 4 + quad;
        unsigned short h0 = f2bf(A[0]), h1 = f2bf(A[1]), h2 = f2bf(A[2]), h3 = f2bf(A[3]);
        uint2 val = make_uint2((unsigned)h0 | ((unsigned)h1 << 16),
                               (unsigned)h2 | ((unsigned)h3 << 16));
        c2u[(size_t)((b * 16 + og) * C2R + (r + 1)) * WW + px] = val;
      }
    }
  }
}

// ---------------------------------------------------------------------------
// k_final: out rows y0, y0+1. Epilogue resamples c2 (uint2 loads, packed
// layout) + min -> out NCHW fp32 via non-temporal stores (write-once).
// ---------------------------------------------------------------------------
__global__ __launch_bounds__(256, 4) void k_final(const unsigned short* __restrict__ xn,
                                                  const unsigned short* __restrict__ Wp,
                                                  const float* __restrict__ s,
                                                  const unsigned short* __restrict__ c2,
                                                  float* __restrict__ out) {
  __shared__ uint4 lds[2112];
  const int t = threadIdx.x;
  const int ctile = blockIdx.x & 3, tr = blockIdx.x >> 2;
  const int b = blockIdx.y;
  const int y0 = tr * 2;
  const int colBase = ctile * 64;

  const uint4* src4 = (const uint4*)xn;
#pragma unroll 1
  for (int i = 0; i < 9; ++i) {
    int idx = i * 256 + t;
    if (idx < 2112) {
      int rr_ = idx / 528, rm = idx % 528;
      int col_ = rm >> 3, ch_ = rm & 7;
      int xrow = y0 - 1 + rr_;  // rows y0-1 .. y0+2
      uint4 v = make_uint4(0, 0, 0, 0);
      if (xrow >= 0 && xrow < HH)
        v = src4[((size_t)(b * HH + xrow) * WP + colBase + col_) * 8 + ch_];
      lds[(rr_ * 66 + col_) * 8 + (ch_ ^ (col_ & 7))] = v;
    }
  }

  const int lane = t & 63, w = t >> 6;
  const int ow = w & 1, ch2 = w >> 1;
  const int quad = lane >> 4, l15 = lane & 15;
  const uint4* wp4 = (const uint4*)Wp;
  __syncthreads();

  f32x4 acc[2][2][2];
#pragma unroll
  for (int pt = 0; pt < 2; ++pt)
#pragma unroll
    for (int rr = 0; rr < 2; ++rr)
#pragma unroll
      for (int ct = 0; ct < 2; ++ct) acc[pt][rr][ct] = {0.f, 0.f, 0.f, 0.f};

#pragma unroll 1
  for (int kc = 0; kc < 2; ++kc) {
    short8 wf[9][2];
#pragma unroll
    for (int tap = 0; tap < 9; ++tap)
#pragma unroll
      for (int ct = 0; ct < 2; ++ct)
        wf[tap][ct] = __builtin_bit_cast(
            short8, wp4[((tap * 4 + (ow * 2 + ct)) * 2 + kc) * 64 + lane]);
#pragma unroll
    for (int pt = 0; pt < 2; ++pt) {
#pragma unroll
      for (int ir = 0; ir < 4; ++ir) {
#pragma unroll
        for (int kx = 0; kx < 3; ++kx) {
          int col = ch2 * 32 + pt * 16 + l15 + kx;
          short8 xf = __builtin_bit_cast(
              short8, lds[(ir * 66 + col) * 8 + ((kc * 4 + quad) ^ (col & 7))]);
          if (ir <= 2) {
#pragma unroll
            for (int ct = 0; ct < 2; ++ct)
              acc[pt][0][ct] = MFMA_BF16(wf[ir * 3 + kx][ct], xf, acc[pt][0][ct], 0, 0, 0);
          }
          if (ir >= 1) {
#pragma unroll
            for (int ct = 0; ct < 2; ++ct)
              acc[pt][1][ct] = MFMA_BF16(wf[(ir - 1) * 3 + kx][ct], xf, acc[pt][1][ct], 0, 0, 0);
          }
        }
      }
    }
  }

  const uint2* c2u = (const uint2*)c2;
#pragma unroll
  for (int pt = 0; pt < 2; ++pt) {
    int px = colBase + ch2 * 32 + pt * 16 + l15;
#pragma unroll
    for (int rr = 0; rr < 2; ++rr) {
      int y = y0 + rr;
      float sv = s[(b * HH + y) * WW + px];
      float ys = (float)y - sv;
      float fy = floorf(ys);
      float wfr = ys - fy;
      int i0 = (int)fy;
      float lw0 = (i0 + 1 >= 0 && i0 + 1 <= HH) ? 1.0f - wfr : 0.0f;
      float lw1 = (i0 + 2 >= 0 && i0 + 2 <= HH) ? wfr : 0.0f;
      int a0 = min(max(i0 + 1, 0), HH);
      int a1 = min(max(i0 + 2, 0), HH);
#pragma unroll
      for (int ct = 0; ct < 2; ++ct) {
        f32x4 A = acc[pt][rr][ct];
        int og = (ow * 2 + ct) * 4 + quad;
        U16x4 v0, v1;
        v0.v = c2u[(size_t)((b * 16 + og) * C2R + a0) * WW + px];
        v1.v = c2u[(size_t)((b * 16 + og) * C2R + a1) * WW + px];
#pragma unroll
        for (int reg = 0; reg < 4; ++reg) {
          float lower = lw0 * bf2f(v0.h[reg]) + lw1 * bf2f(v1.h[reg]);
          __builtin_nontemporal_store(
              fminf(A[reg], lower),
              &out[((size_t)(b * CC + og * 4 + reg) * HH + y) * WW + px]);
        }
      }
    }
  }
}

// ---------------------------------------------------------------------------
extern "C" void kernel_launch(void* const* d_in, const int* in_sizes, int n_in,
                              void* d_out, int out_size, void* d_ws, size_t ws_size,
                              hipStream_t stream) {
  const float* x = (const float*)d_in[0];
  const float* Wt = (const float*)d_in[1];
  float* out = (float*)d_out;

  char* ws = (char*)d_ws;
  float* s = (float*)ws;                                   //   1,048,576 B
  unsigned short* Wp = (unsigned short*)(ws + 1048576);    //      73,728 B
  unsigned short* xn = (unsigned short*)(ws + 1122304);    //  33,816,576 B
  unsigned short* c2 = (unsigned short*)(ws + 34938880);   //  33,685,504 B
                                                           // total 68.6 MB
  k_pack<<<dim3(530, BB), 256, 0, stream>>>(x, Wt, s, Wp, xn);
  k_lower<<<dim3(4 * 129, BB), 256, 0, stream>>>(xn, Wp, s, c2);
  k_final<<<dim3(4 * 128, BB), 256, 0, stream>>>(xn, Wp, s, c2, out);
}